// Round 1
// baseline (850.133 us; speedup 1.0000x reference)
//
#include <hip/hip_runtime.h>
#include <cstdint>

#define NUM_CLASSES 80
#define NPRED 8400
#define NBATCH 32
#define TOPK_N 1000
#define SORTN 16384
#define CONF_T 0.25f
#define NMS_T 0.45f
#define STRIDE 85

__device__ __forceinline__ uint32_t f32_sortable(float f) {
    uint32_t u = __float_as_uint(f);
    return u ^ ((u >> 31) ? 0xFFFFFFFFu : 0x80000000u);
}

// One block per batch: decode scores, build sort keys, bitonic-sort 16384 in LDS,
// emit top-1000 original indices (descending score, ascending index on ties —
// exactly lax.top_k semantics).
__global__ __launch_bounds__(1024) void topk_kernel(const float* __restrict__ pred,
                                                    int* __restrict__ top_idx) {
    __shared__ uint64_t keys[SORTN];              // 128 KiB
    const int b = blockIdx.x;
    const int tid = threadIdx.x;
    const float* pb = pred + (size_t)b * NPRED * STRIDE;

    for (int e = tid; e < SORTN; e += 1024) {
        uint64_t key = 0;  // padding sinks below everything (real keys have high bit patterns >= sortable(-1.0f))
        if (e < NPRED) {
            const float* p = pb + (size_t)e * STRIDE;
            float obj = p[4];
            float best = p[5];
            #pragma unroll 8
            for (int c = 1; c < NUM_CLASSES; ++c) {
                best = fmaxf(best, p[5 + c]);
            }
            float score = __fmul_rn(obj, best);
            float masked = (score >= CONF_T) ? score : -1.0f;
            key = ((uint64_t)f32_sortable(masked) << 32) | (uint32_t)(~(uint32_t)e);
        }
        keys[e] = key;
    }
    __syncthreads();

    // bitonic sort, descending
    for (unsigned k = 2; k <= SORTN; k <<= 1) {
        for (unsigned j = k >> 1; j > 0; j >>= 1) {
            for (unsigned i = tid; i < SORTN; i += 1024) {
                unsigned ixj = i ^ j;
                if (ixj > i) {
                    uint64_t a = keys[i], c = keys[ixj];
                    bool desc = ((i & k) == 0);
                    if (desc ? (a < c) : (a > c)) { keys[i] = c; keys[ixj] = a; }
                }
            }
            __syncthreads();
        }
    }

    for (int t = tid; t < TOPK_N; t += 1024) {
        top_idx[b * TOPK_N + t] = (int)(~(uint32_t)keys[t]);
    }
}

// One block per batch: gather selected rows, re-decode (strict-rounded ops to match
// the numpy reference bit-for-bit), build suppression bitmask matrix in LDS,
// serial greedy reduce with one wave, write dets + keep.
__global__ __launch_bounds__(1024) void nms_kernel(const float* __restrict__ pred,
                                                   const int* __restrict__ top_idx,
                                                   float* __restrict__ dets,
                                                   float* __restrict__ keep_out) {
    __shared__ uint64_t mask[TOPK_N * 16];        // 125 KiB
    __shared__ float lx1[TOPK_N], ly1[TOPK_N], lx2[TOPK_N], ly2[TOPK_N];
    __shared__ float lsc[TOPK_N], lcl[TOPK_N];    // 23.4 KiB
    __shared__ uint64_t removed_w[16];

    const int b = blockIdx.x;
    const int tid = threadIdx.x;
    const float* pb = pred + (size_t)b * NPRED * STRIDE;

    bool invalid = false;
    if (tid < TOPK_N) {
        int e = top_idx[b * TOPK_N + tid];
        const float* p = pb + (size_t)e * STRIDE;
        float cx = p[0], cy = p[1], w = p[2], h = p[3], obj = p[4];
        float best = p[5]; int bc = 0;
        for (int c = 1; c < NUM_CLASSES; ++c) {
            float v = p[5 + c];
            if (v > best) { best = v; bc = c; }   // first-max wins, like jnp.argmax
        }
        float w2 = __fmul_rn(w, 0.5f), h2 = __fmul_rn(h, 0.5f);
        float score = __fmul_rn(obj, best);
        lx1[tid] = __fsub_rn(cx, w2);
        ly1[tid] = __fsub_rn(cy, h2);
        lx2[tid] = __fadd_rn(cx, w2);
        ly2[tid] = __fadd_rn(cy, h2);
        lsc[tid] = score;
        lcl[tid] = (float)bc;
        invalid = (score < CONF_T);
    }
    // initial removed bits = !valid_k ; wave w's ballot is exactly word w (64 lanes)
    {
        uint64_t bal = __ballot(invalid);
        if ((tid & 63) == 0) removed_w[tid >> 6] = bal;
    }
    __syncthreads();

    // suppression mask: bit set iff (j > i) && same class && iou(offset boxes) > 0.45
    for (int p = tid; p < TOPK_N * 16; p += 1024) {
        int i = p >> 4, w = p & 15;
        float ci = lcl[i];
        float offi = __fmul_rn(ci, 10.0f);
        float ax1 = __fadd_rn(lx1[i], offi), ay1 = __fadd_rn(ly1[i], offi);
        float ax2 = __fadd_rn(lx2[i], offi), ay2 = __fadd_rn(ly2[i], offi);
        float areai = __fmul_rn(__fsub_rn(ax2, ax1), __fsub_rn(ay2, ay1));
        uint64_t bits = 0;
        int jend = min(TOPK_N - w * 64, 64);
        for (int bb = 0; bb < jend; ++bb) {
            int j = w * 64 + bb;
            if (j <= i) continue;
            if (lcl[j] != ci) continue;          // different class => offset boxes disjoint => iou == 0
            float bx1 = __fadd_rn(lx1[j], offi), by1 = __fadd_rn(ly1[j], offi);
            float bx2 = __fadd_rn(lx2[j], offi), by2 = __fadd_rn(ly2[j], offi);
            float areaj = __fmul_rn(__fsub_rn(bx2, bx1), __fsub_rn(by2, by1));
            float ix1 = fmaxf(ax1, bx1), iy1 = fmaxf(ay1, by1);
            float ix2 = fminf(ax2, bx2), iy2 = fminf(ay2, by2);
            float dx = fmaxf(__fsub_rn(ix2, ix1), 0.0f);
            float dy = fmaxf(__fsub_rn(iy2, iy1), 0.0f);
            float inter = __fmul_rn(dx, dy);
            float uni = __fsub_rn(__fadd_rn(areai, areaj), inter);
            float iou = __fdiv_rn(inter, fmaxf(uni, 1e-9f));
            if (iou > NMS_T) bits |= (1ull << bb);
        }
        mask[i * 16 + w] = bits;
    }
    __syncthreads();

    // serial greedy reduce: one wave, lanes 0..15 hold removed-bitmask words
    if (tid < 64) {
        int lane = tid;
        uint64_t rem = (lane < 16) ? removed_w[lane] : 0;
        for (int i = 0; i < TOPK_N; ++i) {
            uint64_t rw = __shfl(rem, i >> 6);
            bool alive = ((rw >> (i & 63)) & 1ull) == 0;
            uint64_t m = mask[i * 16 + (lane & 15)];
            if (alive && lane < 16) rem |= m;
        }
        if (lane < 16) removed_w[lane] = rem;
    }
    __syncthreads();

    for (int t = tid; t < TOPK_N; t += 1024) {
        bool kept = ((removed_w[t >> 6] >> (t & 63)) & 1ull) == 0;
        float* dr = dets + ((size_t)b * TOPK_N + t) * 6;
        if (kept) {
            dr[0] = lx1[t]; dr[1] = ly1[t]; dr[2] = lx2[t]; dr[3] = ly2[t];
            dr[4] = lsc[t]; dr[5] = lcl[t];
        } else {
            dr[0] = 0.0f; dr[1] = 0.0f; dr[2] = 0.0f;
            dr[3] = 0.0f; dr[4] = 0.0f; dr[5] = 0.0f;
        }
        keep_out[b * TOPK_N + t] = kept ? 1.0f : 0.0f;
    }
}

extern "C" void kernel_launch(void* const* d_in, const int* in_sizes, int n_in,
                              void* d_out, int out_size, void* d_ws, size_t ws_size,
                              hipStream_t stream) {
    const float* pred = (const float*)d_in[0];
    float* dets = (float*)d_out;                          // 32*1000*6
    float* keep = (float*)d_out + (size_t)NBATCH * TOPK_N * 6;
    int* top_idx = (int*)d_ws;                            // 32*1000 ints = 128 KB

    topk_kernel<<<NBATCH, 1024, 0, stream>>>(pred, top_idx);
    nms_kernel<<<NBATCH, 1024, 0, stream>>>(pred, top_idx, dets, keep);
}

// Round 2
// 398.067 us; speedup vs baseline: 2.1357x; 2.1357x over previous
//
#include <hip/hip_runtime.h>
#include <cstdint>

#define NUM_CLASSES 80
#define NPRED 8400
#define NBATCH 32
#define TOPK_N 1000
#define SORTN 16384
#define CONF_T 0.25f
#define NMS_T 0.45f
#define STRIDE 85

#define ROWS_PB 128
#define FLOATS_PB (ROWS_PB * STRIDE)   // 10880
#define F4_PB (FLOATS_PB / 4)          // 2720

__device__ __forceinline__ uint32_t f32_sortable(float f) {
    uint32_t u = __float_as_uint(f);
    return u ^ ((u >> 31) ? 0xFFFFFFFFu : 0x80000000u);
}

// Full-grid decode: coalesced float4 staging of 128 rows into LDS, per-row
// class-max, emit 64-bit sort key (descending score, ascending index tie-break).
__global__ __launch_bounds__(256) void decode_kernel(const float* __restrict__ pred,
                                                     uint64_t* __restrict__ keys) {
    __shared__ float s[FLOATS_PB];                 // 42.5 KiB
    const int blk = blockIdx.x;
    const int tid = threadIdx.x;
    const float4* g4 = (const float4*)pred + (size_t)blk * F4_PB;
    float4* s4 = (float4*)s;
    for (int i = tid; i < F4_PB; i += 256) s4[i] = g4[i];
    __syncthreads();
    if (tid < ROWS_PB) {
        const float* p = s + tid * STRIDE;         // lane bank stride 85%32=21, coprime -> conflict-free
        float obj = p[4];
        float best = p[5];
        #pragma unroll
        for (int c = 1; c < NUM_CLASSES; ++c) best = fmaxf(best, p[5 + c]);
        float score = __fmul_rn(obj, best);
        float masked = (score >= CONF_T) ? score : -1.0f;
        int r = blk * ROWS_PB + tid;               // global row = b*8400 + e
        int e = r % NPRED;
        keys[r] = ((uint64_t)f32_sortable(masked) << 32) | (uint32_t)(~(uint32_t)e);
    }
}

// One block per batch: exact radix-select of the 1000th-largest unique 64-bit key,
// compact the 1000 winners, bitonic-sort 1024, write indices in lax.top_k order.
__global__ __launch_bounds__(1024) void select_kernel(const uint64_t* __restrict__ keys,
                                                      int* __restrict__ top_idx) {
    __shared__ uint64_t k_lds[NPRED];              // 67.2 KiB
    __shared__ uint64_t sortbuf[1024];             // 8 KiB
    __shared__ uint32_t hist[256];
    __shared__ uint32_t sh_rem, sh_cnt;
    __shared__ uint64_t sh_prefix;
    const int b = blockIdx.x;
    const int tid = threadIdx.x;

    for (int e = tid; e < NPRED; e += 1024) k_lds[e] = keys[(size_t)b * NPRED + e];
    if (tid == 0) { sh_rem = TOPK_N; sh_prefix = 0; sh_cnt = 0; }
    sortbuf[tid] = 0;                              // pads sink (real keys have high word >= sortable(-1.0))
    __syncthreads();

    for (int shift = 56; shift >= 0; shift -= 8) {
        if (tid < 256) hist[tid] = 0;
        __syncthreads();
        uint64_t himask = (shift == 56) ? 0ull : (~0ull << (shift + 8));
        uint64_t pref = sh_prefix;
        for (int e = tid; e < NPRED; e += 1024) {
            uint64_t k = k_lds[e];
            if ((k & himask) == (pref & himask))
                atomicAdd(&hist[(uint32_t)(k >> shift) & 255u], 1u);
        }
        __syncthreads();
        if (tid == 0) {
            uint32_t rem = sh_rem, cum = 0;
            int chosen = 0;
            for (int d = 255; d >= 0; --d) {
                uint32_t h = hist[d];
                if (cum + h >= rem) { chosen = d; sh_rem = rem - cum; break; }
                cum += h;
            }
            sh_prefix = pref | ((uint64_t)(uint32_t)chosen << shift);
        }
        __syncthreads();
    }

    const uint64_t T = sh_prefix;                  // exactly 1000 keys are >= T (keys unique)
    for (int e = tid; e < NPRED; e += 1024) {
        uint64_t k = k_lds[e];
        if (k >= T) {
            uint32_t pos = atomicAdd(&sh_cnt, 1u);
            if (pos < 1024) sortbuf[pos] = k;
        }
    }
    __syncthreads();

    // bitonic sort descending, 1024 elems, 1 compare-exchange per thread per stage
    for (unsigned k = 2; k <= 1024; k <<= 1) {
        for (unsigned j = k >> 1; j > 0; j >>= 1) {
            unsigned i = tid, ixj = i ^ j;
            if (ixj > i) {
                uint64_t a = sortbuf[i], c = sortbuf[ixj];
                bool desc = ((i & k) == 0);
                if (desc ? (a < c) : (a > c)) { sortbuf[i] = c; sortbuf[ixj] = a; }
            }
            __syncthreads();
        }
    }

    if (tid < TOPK_N) top_idx[b * TOPK_N + tid] = (int)(~(uint32_t)sortbuf[tid]);
}

// Fallback (ws too small): original one-block-per-batch full bitonic topk.
__global__ __launch_bounds__(1024) void topk_kernel(const float* __restrict__ pred,
                                                    int* __restrict__ top_idx) {
    __shared__ uint64_t keys[SORTN];
    const int b = blockIdx.x;
    const int tid = threadIdx.x;
    const float* pb = pred + (size_t)b * NPRED * STRIDE;

    for (int e = tid; e < SORTN; e += 1024) {
        uint64_t key = 0;
        if (e < NPRED) {
            const float* p = pb + (size_t)e * STRIDE;
            float obj = p[4];
            float best = p[5];
            #pragma unroll 8
            for (int c = 1; c < NUM_CLASSES; ++c) best = fmaxf(best, p[5 + c]);
            float score = __fmul_rn(obj, best);
            float masked = (score >= CONF_T) ? score : -1.0f;
            key = ((uint64_t)f32_sortable(masked) << 32) | (uint32_t)(~(uint32_t)e);
        }
        keys[e] = key;
    }
    __syncthreads();
    for (unsigned k = 2; k <= SORTN; k <<= 1) {
        for (unsigned j = k >> 1; j > 0; j >>= 1) {
            for (unsigned i = tid; i < SORTN; i += 1024) {
                unsigned ixj = i ^ j;
                if (ixj > i) {
                    uint64_t a = keys[i], c = keys[ixj];
                    bool desc = ((i & k) == 0);
                    if (desc ? (a < c) : (a > c)) { keys[i] = c; keys[ixj] = a; }
                }
            }
            __syncthreads();
        }
    }
    for (int t = tid; t < TOPK_N; t += 1024) {
        top_idx[b * TOPK_N + t] = (int)(~(uint32_t)keys[t]);
    }
}

// One block per batch: gather selected rows, re-decode (strict-rounded ops to match
// the numpy reference bit-for-bit), build suppression bitmask matrix in LDS,
// serial greedy reduce with one wave, write dets + keep.
__global__ __launch_bounds__(1024) void nms_kernel(const float* __restrict__ pred,
                                                   const int* __restrict__ top_idx,
                                                   float* __restrict__ dets,
                                                   float* __restrict__ keep_out) {
    __shared__ uint64_t mask[TOPK_N * 16];         // 125 KiB
    __shared__ float lx1[TOPK_N], ly1[TOPK_N], lx2[TOPK_N], ly2[TOPK_N];
    __shared__ float lsc[TOPK_N], lcl[TOPK_N];
    __shared__ uint64_t removed_w[16];

    const int b = blockIdx.x;
    const int tid = threadIdx.x;
    const float* pb = pred + (size_t)b * NPRED * STRIDE;

    bool invalid = false;
    if (tid < TOPK_N) {
        int e = top_idx[b * TOPK_N + tid];
        const float* p = pb + (size_t)e * STRIDE;
        float cx = p[0], cy = p[1], w = p[2], h = p[3], obj = p[4];
        float best = p[5]; int bc = 0;
        for (int c = 1; c < NUM_CLASSES; ++c) {
            float v = p[5 + c];
            if (v > best) { best = v; bc = c; }    // first-max wins, like jnp.argmax
        }
        float w2 = __fmul_rn(w, 0.5f), h2 = __fmul_rn(h, 0.5f);
        float score = __fmul_rn(obj, best);
        lx1[tid] = __fsub_rn(cx, w2);
        ly1[tid] = __fsub_rn(cy, h2);
        lx2[tid] = __fadd_rn(cx, w2);
        ly2[tid] = __fadd_rn(cy, h2);
        lsc[tid] = score;
        lcl[tid] = (float)bc;
        invalid = (score < CONF_T);
    }
    {
        uint64_t bal = __ballot(invalid);
        if ((tid & 63) == 0) removed_w[tid >> 6] = bal;
    }
    __syncthreads();

    for (int p = tid; p < TOPK_N * 16; p += 1024) {
        int i = p >> 4, w = p & 15;
        float ci = lcl[i];
        float offi = __fmul_rn(ci, 10.0f);
        float ax1 = __fadd_rn(lx1[i], offi), ay1 = __fadd_rn(ly1[i], offi);
        float ax2 = __fadd_rn(lx2[i], offi), ay2 = __fadd_rn(ly2[i], offi);
        float areai = __fmul_rn(__fsub_rn(ax2, ax1), __fsub_rn(ay2, ay1));
        uint64_t bits = 0;
        int jend = min(TOPK_N - w * 64, 64);
        for (int bb = 0; bb < jend; ++bb) {
            int j = w * 64 + bb;
            if (j <= i) continue;
            if (lcl[j] != ci) continue;            // different class => disjoint after +10*class offset
            float bx1 = __fadd_rn(lx1[j], offi), by1 = __fadd_rn(ly1[j], offi);
            float bx2 = __fadd_rn(lx2[j], offi), by2 = __fadd_rn(ly2[j], offi);
            float areaj = __fmul_rn(__fsub_rn(bx2, bx1), __fsub_rn(by2, by1));
            float ix1 = fmaxf(ax1, bx1), iy1 = fmaxf(ay1, by1);
            float ix2 = fminf(ax2, bx2), iy2 = fminf(ay2, by2);
            float dx = fmaxf(__fsub_rn(ix2, ix1), 0.0f);
            float dy = fmaxf(__fsub_rn(iy2, iy1), 0.0f);
            float inter = __fmul_rn(dx, dy);
            float uni = __fsub_rn(__fadd_rn(areai, areaj), inter);
            float iou = __fdiv_rn(inter, fmaxf(uni, 1e-9f));
            if (iou > NMS_T) bits |= (1ull << bb);
        }
        mask[i * 16 + w] = bits;
    }
    __syncthreads();

    if (tid < 64) {
        int lane = tid;
        uint64_t rem = (lane < 16) ? removed_w[lane] : 0;
        for (int i = 0; i < TOPK_N; ++i) {
            uint64_t rw = __shfl(rem, i >> 6);
            bool alive = ((rw >> (i & 63)) & 1ull) == 0;
            uint64_t m = mask[i * 16 + (lane & 15)];
            if (alive && lane < 16) rem |= m;
        }
        if (lane < 16) removed_w[lane] = rem;
    }
    __syncthreads();

    for (int t = tid; t < TOPK_N; t += 1024) {
        bool kept = ((removed_w[t >> 6] >> (t & 63)) & 1ull) == 0;
        float* dr = dets + ((size_t)b * TOPK_N + t) * 6;
        if (kept) {
            dr[0] = lx1[t]; dr[1] = ly1[t]; dr[2] = lx2[t]; dr[3] = ly2[t];
            dr[4] = lsc[t]; dr[5] = lcl[t];
        } else {
            dr[0] = 0.0f; dr[1] = 0.0f; dr[2] = 0.0f;
            dr[3] = 0.0f; dr[4] = 0.0f; dr[5] = 0.0f;
        }
        keep_out[b * TOPK_N + t] = kept ? 1.0f : 0.0f;
    }
}

extern "C" void kernel_launch(void* const* d_in, const int* in_sizes, int n_in,
                              void* d_out, int out_size, void* d_ws, size_t ws_size,
                              hipStream_t stream) {
    const float* pred = (const float*)d_in[0];
    float* dets = (float*)d_out;                              // 32*1000*6
    float* keep = (float*)d_out + (size_t)NBATCH * TOPK_N * 6;

    const size_t keys_bytes = (size_t)NBATCH * NPRED * sizeof(uint64_t);   // 2.15 MB
    const size_t idx_bytes  = (size_t)NBATCH * TOPK_N * sizeof(int);       // 128 KB

    if (ws_size >= keys_bytes + idx_bytes) {
        uint64_t* keys = (uint64_t*)d_ws;
        int* top_idx = (int*)((char*)d_ws + keys_bytes);
        const int total_rows = NBATCH * NPRED;                // 268800
        decode_kernel<<<total_rows / ROWS_PB, 256, 0, stream>>>(pred, keys);
        select_kernel<<<NBATCH, 1024, 0, stream>>>(keys, top_idx);
        nms_kernel<<<NBATCH, 1024, 0, stream>>>(pred, top_idx, dets, keep);
    } else {
        int* top_idx = (int*)d_ws;
        topk_kernel<<<NBATCH, 1024, 0, stream>>>(pred, top_idx);
        nms_kernel<<<NBATCH, 1024, 0, stream>>>(pred, top_idx, dets, keep);
    }
}

// Round 3
// 256.303 us; speedup vs baseline: 3.3169x; 1.5531x over previous
//
#include <hip/hip_runtime.h>
#include <cstdint>

#define NUM_CLASSES 80
#define NPRED 8400
#define NBATCH 32
#define TOPK_N 1000
#define SORTN 16384
#define CONF_T 0.25f
#define NMS_T 0.45f
#define STRIDE 85

#define ROWS_PB 128
#define FLOATS_PB (ROWS_PB * STRIDE)   // 10880
#define F4_PB (FLOATS_PB / 4)          // 2720
#define REC_F 8                        // floats per record (padded to 32B)
#define MPAD 1002                      // LDS mask row pad (breaks bank pattern)

__device__ __forceinline__ uint32_t f32_sortable(float f) {
    uint32_t u = __float_as_uint(f);
    return u ^ ((u >> 31) ? 0xFFFFFFFFu : 0x80000000u);
}

// Full-grid decode: coalesced float4 staging of 128 rows into LDS, per-row
// argmax over 80 classes + box decode. Emits 64-bit sort key and (optionally)
// a 32B record (x1,y1,x2,y2,score,class) so no later stage re-reads pred.
__global__ __launch_bounds__(256) void decode_kernel(const float* __restrict__ pred,
                                                     uint64_t* __restrict__ keys,
                                                     float* __restrict__ recs) {
    __shared__ float s[FLOATS_PB];                 // 42.5 KiB
    const int blk = blockIdx.x;
    const int tid = threadIdx.x;
    const float4* g4 = (const float4*)pred + (size_t)blk * F4_PB;
    float4* s4 = (float4*)s;
    for (int i = tid; i < F4_PB; i += 256) s4[i] = g4[i];
    __syncthreads();
    if (tid < ROWS_PB) {
        const float* p = s + tid * STRIDE;         // stride 85 % 32 = 21, coprime -> conflict-free
        float cx = p[0], cy = p[1], w = p[2], h = p[3], obj = p[4];
        float best = p[5]; int bc = 0;
        #pragma unroll
        for (int c = 1; c < NUM_CLASSES; ++c) {
            float v = p[5 + c];
            if (v > best) { best = v; bc = c; }    // first-max wins, like jnp.argmax
        }
        float w2 = __fmul_rn(w, 0.5f), h2 = __fmul_rn(h, 0.5f);
        float score = __fmul_rn(obj, best);
        float masked = (score >= CONF_T) ? score : -1.0f;
        int r = blk * ROWS_PB + tid;               // global row = b*8400 + e
        int e = r % NPRED;
        keys[r] = ((uint64_t)f32_sortable(masked) << 32) | (uint32_t)(~(uint32_t)e);
        if (recs) {
            float4* rp = (float4*)(recs + (size_t)r * REC_F);
            rp[0] = make_float4(__fsub_rn(cx, w2), __fsub_rn(cy, h2),
                                __fadd_rn(cx, w2), __fadd_rn(cy, h2));
            rp[1] = make_float4(score, (float)bc, 0.0f, 0.0f);
        }
    }
}

// One block per batch: exact radix-select of the 1000th-largest unique 64-bit key,
// compact the 1000 winners, bitonic-sort 1024, write indices in lax.top_k order.
__global__ __launch_bounds__(1024) void select_kernel(const uint64_t* __restrict__ keys,
                                                      int* __restrict__ top_idx) {
    __shared__ uint64_t k_lds[NPRED];              // 67.2 KiB
    __shared__ uint64_t sortbuf[1024];
    __shared__ uint32_t hist[256];
    __shared__ uint32_t sh_rem, sh_cnt;
    __shared__ uint64_t sh_prefix;
    const int b = blockIdx.x;
    const int tid = threadIdx.x;

    for (int e = tid; e < NPRED; e += 1024) k_lds[e] = keys[(size_t)b * NPRED + e];
    if (tid == 0) { sh_rem = TOPK_N; sh_prefix = 0; sh_cnt = 0; }
    sortbuf[tid] = 0;                              // pads sink (real keys' high word >= sortable(-1.0))
    __syncthreads();

    for (int shift = 56; shift >= 0; shift -= 8) {
        if (tid < 256) hist[tid] = 0;
        __syncthreads();
        uint64_t himask = (shift == 56) ? 0ull : (~0ull << (shift + 8));
        uint64_t pref = sh_prefix;
        for (int e = tid; e < NPRED; e += 1024) {
            uint64_t k = k_lds[e];
            if ((k & himask) == (pref & himask))
                atomicAdd(&hist[(uint32_t)(k >> shift) & 255u], 1u);
        }
        __syncthreads();
        if (tid == 0) {
            uint32_t rem = sh_rem, cum = 0;
            int chosen = 0;
            for (int d = 255; d >= 0; --d) {
                uint32_t h = hist[d];
                if (cum + h >= rem) { chosen = d; sh_rem = rem - cum; break; }
                cum += h;
            }
            sh_prefix = pref | ((uint64_t)(uint32_t)chosen << shift);
        }
        __syncthreads();
    }

    const uint64_t T = sh_prefix;                  // exactly 1000 keys >= T (keys unique)
    for (int e = tid; e < NPRED; e += 1024) {
        uint64_t k = k_lds[e];
        if (k >= T) {
            uint32_t pos = atomicAdd(&sh_cnt, 1u);
            if (pos < 1024) sortbuf[pos] = k;
        }
    }
    __syncthreads();

    for (unsigned k = 2; k <= 1024; k <<= 1) {
        for (unsigned j = k >> 1; j > 0; j >>= 1) {
            unsigned i = tid, ixj = i ^ j;
            if (ixj > i) {
                uint64_t a = sortbuf[i], c = sortbuf[ixj];
                bool desc = ((i & k) == 0);
                if (desc ? (a < c) : (a > c)) { sortbuf[i] = c; sortbuf[ixj] = a; }
            }
            __syncthreads();
        }
    }

    if (tid < TOPK_N) top_idx[b * TOPK_N + tid] = (int)(~(uint32_t)sortbuf[tid]);
}

// Mask build, conflict-free: block (w=col-block, b=batch). 64 column boxes staged
// in LDS (offset coords + area precomputed once per box, as the reference does);
// each thread owns 4 rows in registers and sweeps columns -> all LDS reads are
// same-address broadcasts. Mask written coalesced, layout [b][w][i].
__global__ __launch_bounds__(256) void maskbuild_kernel(const float* __restrict__ recs,
                                                        const int* __restrict__ top_idx,
                                                        uint64_t* __restrict__ mask) {
    __shared__ float cx1[64], cy1[64], cx2[64], cy2[64], car[64], ccl[64];
    const int w = blockIdx.x, b = blockIdx.y;
    const int tid = threadIdx.x;
    const int jbase = w * 64;
    const int jend = min(TOPK_N - jbase, 64);

    if (tid < jend) {
        int e = top_idx[b * TOPK_N + jbase + tid];
        const float4* rp = (const float4*)(recs + ((size_t)b * NPRED + e) * REC_F);
        float4 r0 = rp[0], r1 = rp[1];
        float off = __fmul_rn(r1.y, 10.0f);        // exact: class*10 <= 790
        float x1 = __fadd_rn(r0.x, off), y1 = __fadd_rn(r0.y, off);
        float x2 = __fadd_rn(r0.z, off), y2 = __fadd_rn(r0.w, off);
        cx1[tid] = x1; cy1[tid] = y1; cx2[tid] = x2; cy2[tid] = y2;
        car[tid] = __fmul_rn(__fsub_rn(x2, x1), __fsub_rn(y2, y1));
        ccl[tid] = r1.y;
    }
    __syncthreads();

    float rx1[4], ry1[4], rx2[4], ry2[4], rar[4], rcl[4];
    bool rv[4];
    #pragma unroll
    for (int q = 0; q < 4; ++q) {
        int r = tid + q * 256;
        rv[q] = (r < TOPK_N);
        if (rv[q]) {
            int e = top_idx[b * TOPK_N + r];
            const float4* rp = (const float4*)(recs + ((size_t)b * NPRED + e) * REC_F);
            float4 r0 = rp[0], r1 = rp[1];
            float off = __fmul_rn(r1.y, 10.0f);
            float x1 = __fadd_rn(r0.x, off), y1 = __fadd_rn(r0.y, off);
            float x2 = __fadd_rn(r0.z, off), y2 = __fadd_rn(r0.w, off);
            rx1[q] = x1; ry1[q] = y1; rx2[q] = x2; ry2[q] = y2;
            rar[q] = __fmul_rn(__fsub_rn(x2, x1), __fsub_rn(y2, y1));
            rcl[q] = r1.y;
        }
    }

    uint64_t bits[4] = {0, 0, 0, 0};
    for (int bb = 0; bb < jend; ++bb) {
        float jx1 = cx1[bb], jy1 = cy1[bb], jx2 = cx2[bb], jy2 = cy2[bb];
        float jar = car[bb], jcl = ccl[bb];
        int j = jbase + bb;
        #pragma unroll
        for (int q = 0; q < 4; ++q) {
            int r = tid + q * 256;
            if (!rv[q] || j <= r || jcl != rcl[q]) continue;  // diff class => disjoint after offset
            float ix1 = fmaxf(rx1[q], jx1), iy1 = fmaxf(ry1[q], jy1);
            float ix2 = fminf(rx2[q], jx2), iy2 = fminf(ry2[q], jy2);
            float dx = fmaxf(__fsub_rn(ix2, ix1), 0.0f);
            float dy = fmaxf(__fsub_rn(iy2, iy1), 0.0f);
            float inter = __fmul_rn(dx, dy);
            float uni = __fsub_rn(__fadd_rn(rar[q], jar), inter);
            float iou = __fdiv_rn(inter, fmaxf(uni, 1e-9f));
            if (iou > NMS_T) bits[q] |= (1ull << bb);
        }
    }
    #pragma unroll
    for (int q = 0; q < 4; ++q) {
        int r = tid + q * 256;
        if (rv[q]) mask[((size_t)b * 16 + w) * TOPK_N + r] = bits[q];
    }
}

// One block per batch: gather records, ballot invalid, mask -> LDS, one-wave
// serial greedy reduce, write dets + keep.
__global__ __launch_bounds__(1024) void reduce_kernel(const float* __restrict__ recs,
                                                      const int* __restrict__ top_idx,
                                                      const uint64_t* __restrict__ mask,
                                                      float* __restrict__ dets,
                                                      float* __restrict__ keep_out) {
    __shared__ uint64_t lmask[16 * MPAD];          // 125.3 KiB
    __shared__ uint64_t removed_w[16];
    const int b = blockIdx.x, tid = threadIdx.x;

    float4 r0 = make_float4(0, 0, 0, 0), r1 = make_float4(0, 0, 0, 0);
    bool invalid = false;
    if (tid < TOPK_N) {
        int e = top_idx[b * TOPK_N + tid];
        const float4* rp = (const float4*)(recs + ((size_t)b * NPRED + e) * REC_F);
        r0 = rp[0]; r1 = rp[1];
        invalid = (r1.x < CONF_T);
    }
    {
        uint64_t bal = __ballot(invalid);
        if ((tid & 63) == 0) removed_w[tid >> 6] = bal;
    }
    for (int p = tid; p < 16 * TOPK_N; p += 1024) {
        int w = p / TOPK_N, i = p - w * TOPK_N;
        lmask[w * MPAD + i] = mask[((size_t)b * 16 + w) * TOPK_N + i];
    }
    __syncthreads();

    if (tid < 64) {
        uint64_t rem = (tid < 16) ? removed_w[tid] : 0;
        for (int i = 0; i < TOPK_N; ++i) {
            uint64_t rw = __shfl(rem, i >> 6);
            bool alive = ((rw >> (i & 63)) & 1ull) == 0;
            uint64_t m = lmask[(tid & 15) * MPAD + i];
            if (alive && tid < 16) rem |= m;
        }
        if (tid < 16) removed_w[tid] = rem;
    }
    __syncthreads();

    if (tid < TOPK_N) {
        bool kept = ((removed_w[tid >> 6] >> (tid & 63)) & 1ull) == 0;
        float* dr = dets + ((size_t)b * TOPK_N + tid) * 6;
        if (kept) {
            dr[0] = r0.x; dr[1] = r0.y; dr[2] = r0.z; dr[3] = r0.w;
            dr[4] = r1.x; dr[5] = r1.y;
        } else {
            dr[0] = 0.0f; dr[1] = 0.0f; dr[2] = 0.0f;
            dr[3] = 0.0f; dr[4] = 0.0f; dr[5] = 0.0f;
        }
        keep_out[b * TOPK_N + tid] = kept ? 1.0f : 0.0f;
    }
}

// ---------- fallback kernels (small ws) ----------

__global__ __launch_bounds__(1024) void topk_kernel(const float* __restrict__ pred,
                                                    int* __restrict__ top_idx) {
    __shared__ uint64_t keys[SORTN];
    const int b = blockIdx.x;
    const int tid = threadIdx.x;
    const float* pb = pred + (size_t)b * NPRED * STRIDE;

    for (int e = tid; e < SORTN; e += 1024) {
        uint64_t key = 0;
        if (e < NPRED) {
            const float* p = pb + (size_t)e * STRIDE;
            float obj = p[4];
            float best = p[5];
            #pragma unroll 8
            for (int c = 1; c < NUM_CLASSES; ++c) best = fmaxf(best, p[5 + c]);
            float score = __fmul_rn(obj, best);
            float masked = (score >= CONF_T) ? score : -1.0f;
            key = ((uint64_t)f32_sortable(masked) << 32) | (uint32_t)(~(uint32_t)e);
        }
        keys[e] = key;
    }
    __syncthreads();
    for (unsigned k = 2; k <= SORTN; k <<= 1) {
        for (unsigned j = k >> 1; j > 0; j >>= 1) {
            for (unsigned i = tid; i < SORTN; i += 1024) {
                unsigned ixj = i ^ j;
                if (ixj > i) {
                    uint64_t a = keys[i], c = keys[ixj];
                    bool desc = ((i & k) == 0);
                    if (desc ? (a < c) : (a > c)) { keys[i] = c; keys[ixj] = a; }
                }
            }
            __syncthreads();
        }
    }
    for (int t = tid; t < TOPK_N; t += 1024) {
        top_idx[b * TOPK_N + t] = (int)(~(uint32_t)keys[t]);
    }
}

__global__ __launch_bounds__(1024) void nms_kernel(const float* __restrict__ pred,
                                                   const int* __restrict__ top_idx,
                                                   float* __restrict__ dets,
                                                   float* __restrict__ keep_out) {
    __shared__ uint64_t mask[TOPK_N * 16];
    __shared__ float lx1[TOPK_N], ly1[TOPK_N], lx2[TOPK_N], ly2[TOPK_N];
    __shared__ float lsc[TOPK_N], lcl[TOPK_N];
    __shared__ uint64_t removed_w[16];

    const int b = blockIdx.x;
    const int tid = threadIdx.x;
    const float* pb = pred + (size_t)b * NPRED * STRIDE;

    bool invalid = false;
    if (tid < TOPK_N) {
        int e = top_idx[b * TOPK_N + tid];
        const float* p = pb + (size_t)e * STRIDE;
        float cx = p[0], cy = p[1], w = p[2], h = p[3], obj = p[4];
        float best = p[5]; int bc = 0;
        for (int c = 1; c < NUM_CLASSES; ++c) {
            float v = p[5 + c];
            if (v > best) { best = v; bc = c; }
        }
        float w2 = __fmul_rn(w, 0.5f), h2 = __fmul_rn(h, 0.5f);
        float score = __fmul_rn(obj, best);
        lx1[tid] = __fsub_rn(cx, w2);
        ly1[tid] = __fsub_rn(cy, h2);
        lx2[tid] = __fadd_rn(cx, w2);
        ly2[tid] = __fadd_rn(cy, h2);
        lsc[tid] = score;
        lcl[tid] = (float)bc;
        invalid = (score < CONF_T);
    }
    {
        uint64_t bal = __ballot(invalid);
        if ((tid & 63) == 0) removed_w[tid >> 6] = bal;
    }
    __syncthreads();

    for (int p = tid; p < TOPK_N * 16; p += 1024) {
        int i = p >> 4, w = p & 15;
        float ci = lcl[i];
        float offi = __fmul_rn(ci, 10.0f);
        float ax1 = __fadd_rn(lx1[i], offi), ay1 = __fadd_rn(ly1[i], offi);
        float ax2 = __fadd_rn(lx2[i], offi), ay2 = __fadd_rn(ly2[i], offi);
        float areai = __fmul_rn(__fsub_rn(ax2, ax1), __fsub_rn(ay2, ay1));
        uint64_t bits = 0;
        int jend = min(TOPK_N - w * 64, 64);
        for (int bb = 0; bb < jend; ++bb) {
            int j = w * 64 + bb;
            if (j <= i) continue;
            if (lcl[j] != ci) continue;
            float bx1 = __fadd_rn(lx1[j], offi), by1 = __fadd_rn(ly1[j], offi);
            float bx2 = __fadd_rn(lx2[j], offi), by2 = __fadd_rn(ly2[j], offi);
            float areaj = __fmul_rn(__fsub_rn(bx2, bx1), __fsub_rn(by2, by1));
            float ix1 = fmaxf(ax1, bx1), iy1 = fmaxf(ay1, by1);
            float ix2 = fminf(ax2, bx2), iy2 = fminf(ay2, by2);
            float dx = fmaxf(__fsub_rn(ix2, ix1), 0.0f);
            float dy = fmaxf(__fsub_rn(iy2, iy1), 0.0f);
            float inter = __fmul_rn(dx, dy);
            float uni = __fsub_rn(__fadd_rn(areai, areaj), inter);
            float iou = __fdiv_rn(inter, fmaxf(uni, 1e-9f));
            if (iou > NMS_T) bits |= (1ull << bb);
        }
        mask[i * 16 + w] = bits;
    }
    __syncthreads();

    if (tid < 64) {
        int lane = tid;
        uint64_t rem = (lane < 16) ? removed_w[lane] : 0;
        for (int i = 0; i < TOPK_N; ++i) {
            uint64_t rw = __shfl(rem, i >> 6);
            bool alive = ((rw >> (i & 63)) & 1ull) == 0;
            uint64_t m = mask[i * 16 + (lane & 15)];
            if (alive && lane < 16) rem |= m;
        }
        if (lane < 16) removed_w[lane] = rem;
    }
    __syncthreads();

    for (int t = tid; t < TOPK_N; t += 1024) {
        bool kept = ((removed_w[t >> 6] >> (t & 63)) & 1ull) == 0;
        float* dr = dets + ((size_t)b * TOPK_N + t) * 6;
        if (kept) {
            dr[0] = lx1[t]; dr[1] = ly1[t]; dr[2] = lx2[t]; dr[3] = ly2[t];
            dr[4] = lsc[t]; dr[5] = lcl[t];
        } else {
            dr[0] = 0.0f; dr[1] = 0.0f; dr[2] = 0.0f;
            dr[3] = 0.0f; dr[4] = 0.0f; dr[5] = 0.0f;
        }
        keep_out[b * TOPK_N + t] = kept ? 1.0f : 0.0f;
    }
}

extern "C" void kernel_launch(void* const* d_in, const int* in_sizes, int n_in,
                              void* d_out, int out_size, void* d_ws, size_t ws_size,
                              hipStream_t stream) {
    const float* pred = (const float*)d_in[0];
    float* dets = (float*)d_out;                              // 32*1000*6
    float* keep = (float*)d_out + (size_t)NBATCH * TOPK_N * 6;

    const size_t total_rows = (size_t)NBATCH * NPRED;         // 268800
    const size_t keys_bytes = total_rows * sizeof(uint64_t);  // 2,150,400
    const size_t recs_bytes = total_rows * REC_F * sizeof(float); // 8,601,600
    const size_t idx_bytes  = (size_t)NBATCH * TOPK_N * sizeof(int); // 128,000
    const size_t mask_bytes = (size_t)NBATCH * 16 * TOPK_N * sizeof(uint64_t); // 4,096,000

    if (ws_size >= keys_bytes + recs_bytes + idx_bytes + mask_bytes) {
        uint64_t* keys = (uint64_t*)d_ws;
        float* recs    = (float*)((char*)d_ws + keys_bytes);
        int* top_idx   = (int*)((char*)d_ws + keys_bytes + recs_bytes);
        uint64_t* mask = (uint64_t*)((char*)d_ws + keys_bytes + recs_bytes + idx_bytes);

        decode_kernel<<<(int)(total_rows / ROWS_PB), 256, 0, stream>>>(pred, keys, recs);
        select_kernel<<<NBATCH, 1024, 0, stream>>>(keys, top_idx);
        maskbuild_kernel<<<dim3(16, NBATCH), 256, 0, stream>>>(recs, top_idx, mask);
        reduce_kernel<<<NBATCH, 1024, 0, stream>>>(recs, top_idx, mask, dets, keep);
    } else if (ws_size >= keys_bytes + idx_bytes) {
        uint64_t* keys = (uint64_t*)d_ws;
        int* top_idx = (int*)((char*)d_ws + keys_bytes);
        decode_kernel<<<(int)(total_rows / ROWS_PB), 256, 0, stream>>>(pred, keys, nullptr);
        select_kernel<<<NBATCH, 1024, 0, stream>>>(keys, top_idx);
        nms_kernel<<<NBATCH, 1024, 0, stream>>>(pred, top_idx, dets, keep);
    } else {
        int* top_idx = (int*)d_ws;
        topk_kernel<<<NBATCH, 1024, 0, stream>>>(pred, top_idx);
        nms_kernel<<<NBATCH, 1024, 0, stream>>>(pred, top_idx, dets, keep);
    }
}

// Round 4
// 182.329 us; speedup vs baseline: 4.6626x; 1.4057x over previous
//
#include <hip/hip_runtime.h>
#include <cstdint>

#define NUM_CLASSES 80
#define NPRED 8400
#define NBATCH 32
#define TOPK_N 1000
#define SORTN 16384
#define CONF_T 0.25f
#define NMS_T 0.45f
#define STRIDE 85

#define ROWS_PB 128
#define FLOATS_PB (ROWS_PB * STRIDE)   // 10880
#define F4_PB (FLOATS_PB / 4)          // 2720
#define REC_F 8                        // floats per record (padded to 32B)
#define MPAD 1002                      // LDS mask row pad (breaks bank pattern)

__device__ __forceinline__ uint32_t f32_sortable(float f) {
    uint32_t u = __float_as_uint(f);
    return u ^ ((u >> 31) ? 0xFFFFFFFFu : 0x80000000u);
}

// 46-bit key: (sortable(masked_score) << 14) | (16383 - e).
// Descending key order == descending score, ascending index on ties (lax.top_k).

// Full-grid decode: coalesced float4 staging of 128 rows into LDS, per-row
// argmax over 80 classes + box decode. Emits sort key and (optionally)
// a 32B record (x1,y1,x2,y2,score,class) so no later stage re-reads pred.
__global__ __launch_bounds__(256) void decode_kernel(const float* __restrict__ pred,
                                                     uint64_t* __restrict__ keys,
                                                     float* __restrict__ recs) {
    __shared__ float s[FLOATS_PB];                 // 42.5 KiB
    const int blk = blockIdx.x;
    const int tid = threadIdx.x;
    const float4* g4 = (const float4*)pred + (size_t)blk * F4_PB;
    float4* s4 = (float4*)s;
    for (int i = tid; i < F4_PB; i += 256) s4[i] = g4[i];
    __syncthreads();
    if (tid < ROWS_PB) {
        const float* p = s + tid * STRIDE;         // stride 85 % 32 = 21, coprime -> conflict-free
        float cx = p[0], cy = p[1], w = p[2], h = p[3], obj = p[4];
        float best = p[5]; int bc = 0;
        #pragma unroll
        for (int c = 1; c < NUM_CLASSES; ++c) {
            float v = p[5 + c];
            if (v > best) { best = v; bc = c; }    // first-max wins, like jnp.argmax
        }
        float w2 = __fmul_rn(w, 0.5f), h2 = __fmul_rn(h, 0.5f);
        float score = __fmul_rn(obj, best);
        float masked = (score >= CONF_T) ? score : -1.0f;
        int r = blk * ROWS_PB + tid;               // global row = b*8400 + e
        int e = r % NPRED;
        keys[r] = ((uint64_t)f32_sortable(masked) << 14) | (uint32_t)(16383 - e);
        if (recs) {
            float4* rp = (float4*)(recs + (size_t)r * REC_F);
            rp[0] = make_float4(__fsub_rn(cx, w2), __fsub_rn(cy, h2),
                                __fadd_rn(cx, w2), __fadd_rn(cy, h2));
            rp[1] = make_float4(score, (float)bc, 0.0f, 0.0f);
        }
    }
}

// One block per batch: exact radix-select (4 x 12-bit MSB passes, parallel
// suffix-scan bin selection), compact the exactly-1000 winners, bitonic-sort
// 1024, write indices in lax.top_k order.
__global__ __launch_bounds__(1024) void select_kernel(const uint64_t* __restrict__ keys,
                                                      int* __restrict__ top_idx) {
    __shared__ uint64_t k_lds[NPRED];              // 67.2 KiB
    __shared__ uint64_t sortbuf[1024];             // 8 KiB
    __shared__ uint32_t hist[4096];                // 16 KiB
    __shared__ uint32_t wtot[16];
    __shared__ uint32_t sh_rem, sh_cnt;
    __shared__ uint64_t sh_prefix;
    const int b = blockIdx.x;
    const int tid = threadIdx.x;
    const int lane = tid & 63, wid = tid >> 6;

    for (int e = tid; e < NPRED; e += 1024) k_lds[e] = keys[(size_t)b * NPRED + e];
    if (tid == 0) { sh_rem = TOPK_N; sh_prefix = 0; sh_cnt = 0; }
    sortbuf[tid] = 0;                              // pads sink (real keys are much larger)
    __syncthreads();

    for (int shift = 36; shift >= 0; shift -= 12) {
        #pragma unroll
        for (int i = 0; i < 4; ++i) hist[tid * 4 + i] = 0;
        __syncthreads();                            // zero visible; prev-pass sh_* writes visible
        const uint64_t himask = (shift == 36) ? 0ull : (~0ull << (shift + 12));
        const uint64_t pref = sh_prefix;
        const uint32_t rem = sh_rem;
        for (int e = tid; e < NPRED; e += 1024) {
            uint64_t k = k_lds[e];
            if ((k & himask) == (pref & himask))
                atomicAdd(&hist[(uint32_t)(k >> shift) & 4095u], 1u);
        }
        __syncthreads();
        // each thread owns bins [4*tid .. 4*tid+3]; suffix sums descending
        uint32_t h0 = hist[tid * 4 + 0], h1 = hist[tid * 4 + 1];
        uint32_t h2 = hist[tid * 4 + 2], h3 = hist[tid * 4 + 3];
        uint32_t s4 = h0 + h1 + h2 + h3;
        uint32_t v = s4;
        #pragma unroll
        for (int off = 1; off < 64; off <<= 1) {   // wave inclusive suffix scan
            uint32_t u = __shfl_down(v, off);
            if (lane + off < 64) v += u;
        }
        if (lane == 0) wtot[wid] = v;
        __syncthreads();
        uint32_t carry = 0;
        for (int w = wid + 1; w < 16; ++w) carry += wtot[w];
        uint32_t S0 = v + carry;                   // sum of hist over bins >= 4*tid
        uint32_t carry_after = S0 - s4;            // sum over bins > 4*tid+3
        if (carry_after < rem && S0 >= rem) {      // exactly one thread: crossing in my 4 bins
            uint32_t hh[4] = {h0, h1, h2, h3};
            uint32_t pre = 0, bestS = S0, besth = h0;
            int besti = 0;
            #pragma unroll
            for (int i = 0; i < 4; ++i) {          // largest i with S(4t+i) >= rem
                uint32_t Si = S0 - pre;
                if (Si >= rem) { besti = i; bestS = Si; besth = hh[i]; }
                pre += hh[i];
            }
            sh_prefix = pref | ((uint64_t)(uint32_t)(tid * 4 + besti) << shift);
            sh_rem = rem - (bestS - besth);        // rem minus count strictly above chosen bin
        }
        __syncthreads();
    }

    const uint64_t T = sh_prefix;                  // exactly 1000 keys >= T (keys unique)
    for (int e = tid; e < NPRED; e += 1024) {
        uint64_t k = k_lds[e];
        if (k >= T) {
            uint32_t pos = atomicAdd(&sh_cnt, 1u);
            if (pos < 1024) sortbuf[pos] = k;
        }
    }
    __syncthreads();

    for (unsigned k = 2; k <= 1024; k <<= 1) {     // bitonic sort descending
        for (unsigned j = k >> 1; j > 0; j >>= 1) {
            unsigned i = tid, ixj = i ^ j;
            if (ixj > i) {
                uint64_t a = sortbuf[i], c = sortbuf[ixj];
                bool desc = ((i & k) == 0);
                if (desc ? (a < c) : (a > c)) { sortbuf[i] = c; sortbuf[ixj] = a; }
            }
            __syncthreads();
        }
    }

    if (tid < TOPK_N)
        top_idx[b * TOPK_N + tid] = 16383 - (int)((uint32_t)sortbuf[tid] & 16383u);
}

// Mask build, conflict-free: block (w=col-block, b=batch). 64 column boxes staged
// in LDS (offset coords + area precomputed once per box); each thread owns 4 rows
// in registers and sweeps columns -> all LDS reads are same-address broadcasts.
__global__ __launch_bounds__(256) void maskbuild_kernel(const float* __restrict__ recs,
                                                        const int* __restrict__ top_idx,
                                                        uint64_t* __restrict__ mask) {
    __shared__ float cx1[64], cy1[64], cx2[64], cy2[64], car[64], ccl[64];
    const int w = blockIdx.x, b = blockIdx.y;
    const int tid = threadIdx.x;
    const int jbase = w * 64;
    const int jend = min(TOPK_N - jbase, 64);

    if (tid < jend) {
        int e = top_idx[b * TOPK_N + jbase + tid];
        const float4* rp = (const float4*)(recs + ((size_t)b * NPRED + e) * REC_F);
        float4 r0 = rp[0], r1 = rp[1];
        float off = __fmul_rn(r1.y, 10.0f);        // exact: class*10 <= 790
        float x1 = __fadd_rn(r0.x, off), y1 = __fadd_rn(r0.y, off);
        float x2 = __fadd_rn(r0.z, off), y2 = __fadd_rn(r0.w, off);
        cx1[tid] = x1; cy1[tid] = y1; cx2[tid] = x2; cy2[tid] = y2;
        car[tid] = __fmul_rn(__fsub_rn(x2, x1), __fsub_rn(y2, y1));
        ccl[tid] = r1.y;
    }
    __syncthreads();

    float rx1[4], ry1[4], rx2[4], ry2[4], rar[4], rcl[4];
    bool rv[4];
    #pragma unroll
    for (int q = 0; q < 4; ++q) {
        int r = tid + q * 256;
        rv[q] = (r < TOPK_N);
        if (rv[q]) {
            int e = top_idx[b * TOPK_N + r];
            const float4* rp = (const float4*)(recs + ((size_t)b * NPRED + e) * REC_F);
            float4 r0 = rp[0], r1 = rp[1];
            float off = __fmul_rn(r1.y, 10.0f);
            float x1 = __fadd_rn(r0.x, off), y1 = __fadd_rn(r0.y, off);
            float x2 = __fadd_rn(r0.z, off), y2 = __fadd_rn(r0.w, off);
            rx1[q] = x1; ry1[q] = y1; rx2[q] = x2; ry2[q] = y2;
            rar[q] = __fmul_rn(__fsub_rn(x2, x1), __fsub_rn(y2, y1));
            rcl[q] = r1.y;
        }
    }

    uint64_t bits[4] = {0, 0, 0, 0};
    for (int bb = 0; bb < jend; ++bb) {
        float jx1 = cx1[bb], jy1 = cy1[bb], jx2 = cx2[bb], jy2 = cy2[bb];
        float jar = car[bb], jcl = ccl[bb];
        int j = jbase + bb;
        #pragma unroll
        for (int q = 0; q < 4; ++q) {
            int r = tid + q * 256;
            if (!rv[q] || j <= r || jcl != rcl[q]) continue;  // diff class => disjoint after offset
            float ix1 = fmaxf(rx1[q], jx1), iy1 = fmaxf(ry1[q], jy1);
            float ix2 = fminf(rx2[q], jx2), iy2 = fminf(ry2[q], jy2);
            float dx = fmaxf(__fsub_rn(ix2, ix1), 0.0f);
            float dy = fmaxf(__fsub_rn(iy2, iy1), 0.0f);
            float inter = __fmul_rn(dx, dy);
            float uni = __fsub_rn(__fadd_rn(rar[q], jar), inter);
            float iou = __fdiv_rn(inter, fmaxf(uni, 1e-9f));
            if (iou > NMS_T) bits[q] |= (1ull << bb);
        }
    }
    #pragma unroll
    for (int q = 0; q < 4; ++q) {
        int r = tid + q * 256;
        if (rv[q]) mask[((size_t)b * 16 + w) * TOPK_N + r] = bits[q];
    }
}

// One block per batch: gather records, ballot invalid, mask -> LDS, one-wave
// serial greedy reduce, write dets + keep.
__global__ __launch_bounds__(1024) void reduce_kernel(const float* __restrict__ recs,
                                                      const int* __restrict__ top_idx,
                                                      const uint64_t* __restrict__ mask,
                                                      float* __restrict__ dets,
                                                      float* __restrict__ keep_out) {
    __shared__ uint64_t lmask[16 * MPAD];          // 125.3 KiB
    __shared__ uint64_t removed_w[16];
    const int b = blockIdx.x, tid = threadIdx.x;

    float4 r0 = make_float4(0, 0, 0, 0), r1 = make_float4(0, 0, 0, 0);
    bool invalid = false;
    if (tid < TOPK_N) {
        int e = top_idx[b * TOPK_N + tid];
        const float4* rp = (const float4*)(recs + ((size_t)b * NPRED + e) * REC_F);
        r0 = rp[0]; r1 = rp[1];
        invalid = (r1.x < CONF_T);
    }
    {
        uint64_t bal = __ballot(invalid);
        if ((tid & 63) == 0) removed_w[tid >> 6] = bal;
    }
    for (int p = tid; p < 16 * TOPK_N; p += 1024) {
        int w = p / TOPK_N, i = p - w * TOPK_N;
        lmask[w * MPAD + i] = mask[((size_t)b * 16 + w) * TOPK_N + i];
    }
    __syncthreads();

    if (tid < 64) {
        uint64_t rem = (tid < 16) ? removed_w[tid] : 0;
        for (int i = 0; i < TOPK_N; ++i) {
            uint64_t rw = __shfl(rem, i >> 6);
            bool alive = ((rw >> (i & 63)) & 1ull) == 0;
            uint64_t m = lmask[(tid & 15) * MPAD + i];
            if (alive && tid < 16) rem |= m;
        }
        if (tid < 16) removed_w[tid] = rem;
    }
    __syncthreads();

    if (tid < TOPK_N) {
        bool kept = ((removed_w[tid >> 6] >> (tid & 63)) & 1ull) == 0;
        float* dr = dets + ((size_t)b * TOPK_N + tid) * 6;
        if (kept) {
            dr[0] = r0.x; dr[1] = r0.y; dr[2] = r0.z; dr[3] = r0.w;
            dr[4] = r1.x; dr[5] = r1.y;
        } else {
            dr[0] = 0.0f; dr[1] = 0.0f; dr[2] = 0.0f;
            dr[3] = 0.0f; dr[4] = 0.0f; dr[5] = 0.0f;
        }
        keep_out[b * TOPK_N + tid] = kept ? 1.0f : 0.0f;
    }
}

// ---------- fallback kernels (small ws) ----------

__global__ __launch_bounds__(1024) void topk_kernel(const float* __restrict__ pred,
                                                    int* __restrict__ top_idx) {
    __shared__ uint64_t keys[SORTN];
    const int b = blockIdx.x;
    const int tid = threadIdx.x;
    const float* pb = pred + (size_t)b * NPRED * STRIDE;

    for (int e = tid; e < SORTN; e += 1024) {
        uint64_t key = 0;
        if (e < NPRED) {
            const float* p = pb + (size_t)e * STRIDE;
            float obj = p[4];
            float best = p[5];
            #pragma unroll 8
            for (int c = 1; c < NUM_CLASSES; ++c) best = fmaxf(best, p[5 + c]);
            float score = __fmul_rn(obj, best);
            float masked = (score >= CONF_T) ? score : -1.0f;
            key = ((uint64_t)f32_sortable(masked) << 32) | (uint32_t)(~(uint32_t)e);
        }
        keys[e] = key;
    }
    __syncthreads();
    for (unsigned k = 2; k <= SORTN; k <<= 1) {
        for (unsigned j = k >> 1; j > 0; j >>= 1) {
            for (unsigned i = tid; i < SORTN; i += 1024) {
                unsigned ixj = i ^ j;
                if (ixj > i) {
                    uint64_t a = keys[i], c = keys[ixj];
                    bool desc = ((i & k) == 0);
                    if (desc ? (a < c) : (a > c)) { keys[i] = c; keys[ixj] = a; }
                }
            }
            __syncthreads();
        }
    }
    for (int t = tid; t < TOPK_N; t += 1024) {
        top_idx[b * TOPK_N + t] = (int)(~(uint32_t)keys[t]);
    }
}

__global__ __launch_bounds__(1024) void nms_kernel(const float* __restrict__ pred,
                                                   const int* __restrict__ top_idx,
                                                   float* __restrict__ dets,
                                                   float* __restrict__ keep_out) {
    __shared__ uint64_t mask[TOPK_N * 16];
    __shared__ float lx1[TOPK_N], ly1[TOPK_N], lx2[TOPK_N], ly2[TOPK_N];
    __shared__ float lsc[TOPK_N], lcl[TOPK_N];
    __shared__ uint64_t removed_w[16];

    const int b = blockIdx.x;
    const int tid = threadIdx.x;
    const float* pb = pred + (size_t)b * NPRED * STRIDE;

    bool invalid = false;
    if (tid < TOPK_N) {
        int e = top_idx[b * TOPK_N + tid];
        const float* p = pb + (size_t)e * STRIDE;
        float cx = p[0], cy = p[1], w = p[2], h = p[3], obj = p[4];
        float best = p[5]; int bc = 0;
        for (int c = 1; c < NUM_CLASSES; ++c) {
            float v = p[5 + c];
            if (v > best) { best = v; bc = c; }
        }
        float w2 = __fmul_rn(w, 0.5f), h2 = __fmul_rn(h, 0.5f);
        float score = __fmul_rn(obj, best);
        lx1[tid] = __fsub_rn(cx, w2);
        ly1[tid] = __fsub_rn(cy, h2);
        lx2[tid] = __fadd_rn(cx, w2);
        ly2[tid] = __fadd_rn(cy, h2);
        lsc[tid] = score;
        lcl[tid] = (float)bc;
        invalid = (score < CONF_T);
    }
    {
        uint64_t bal = __ballot(invalid);
        if ((tid & 63) == 0) removed_w[tid >> 6] = bal;
    }
    __syncthreads();

    for (int p = tid; p < TOPK_N * 16; p += 1024) {
        int i = p >> 4, w = p & 15;
        float ci = lcl[i];
        float offi = __fmul_rn(ci, 10.0f);
        float ax1 = __fadd_rn(lx1[i], offi), ay1 = __fadd_rn(ly1[i], offi);
        float ax2 = __fadd_rn(lx2[i], offi), ay2 = __fadd_rn(ly2[i], offi);
        float areai = __fmul_rn(__fsub_rn(ax2, ax1), __fsub_rn(ay2, ay1));
        uint64_t bits = 0;
        int jend = min(TOPK_N - w * 64, 64);
        for (int bb = 0; bb < jend; ++bb) {
            int j = w * 64 + bb;
            if (j <= i) continue;
            if (lcl[j] != ci) continue;
            float bx1 = __fadd_rn(lx1[j], offi), by1 = __fadd_rn(ly1[j], offi);
            float bx2 = __fadd_rn(lx2[j], offi), by2 = __fadd_rn(ly2[j], offi);
            float areaj = __fmul_rn(__fsub_rn(bx2, bx1), __fsub_rn(by2, by1));
            float ix1 = fmaxf(ax1, bx1), iy1 = fmaxf(ay1, by1);
            float ix2 = fminf(ax2, bx2), iy2 = fminf(ay2, by2);
            float dx = fmaxf(__fsub_rn(ix2, ix1), 0.0f);
            float dy = fmaxf(__fsub_rn(iy2, iy1), 0.0f);
            float inter = __fmul_rn(dx, dy);
            float uni = __fsub_rn(__fadd_rn(areai, areaj), inter);
            float iou = __fdiv_rn(inter, fmaxf(uni, 1e-9f));
            if (iou > NMS_T) bits |= (1ull << bb);
        }
        mask[i * 16 + w] = bits;
    }
    __syncthreads();

    if (tid < 64) {
        int lane = tid;
        uint64_t rem = (lane < 16) ? removed_w[lane] : 0;
        for (int i = 0; i < TOPK_N; ++i) {
            uint64_t rw = __shfl(rem, i >> 6);
            bool alive = ((rw >> (i & 63)) & 1ull) == 0;
            uint64_t m = mask[i * 16 + (lane & 15)];
            if (alive && lane < 16) rem |= m;
        }
        if (lane < 16) removed_w[lane] = rem;
    }
    __syncthreads();

    for (int t = tid; t < TOPK_N; t += 1024) {
        bool kept = ((removed_w[t >> 6] >> (t & 63)) & 1ull) == 0;
        float* dr = dets + ((size_t)b * TOPK_N + t) * 6;
        if (kept) {
            dr[0] = lx1[t]; dr[1] = ly1[t]; dr[2] = lx2[t]; dr[3] = ly2[t];
            dr[4] = lsc[t]; dr[5] = lcl[t];
        } else {
            dr[0] = 0.0f; dr[1] = 0.0f; dr[2] = 0.0f;
            dr[3] = 0.0f; dr[4] = 0.0f; dr[5] = 0.0f;
        }
        keep_out[b * TOPK_N + t] = kept ? 1.0f : 0.0f;
    }
}

extern "C" void kernel_launch(void* const* d_in, const int* in_sizes, int n_in,
                              void* d_out, int out_size, void* d_ws, size_t ws_size,
                              hipStream_t stream) {
    const float* pred = (const float*)d_in[0];
    float* dets = (float*)d_out;                              // 32*1000*6
    float* keep = (float*)d_out + (size_t)NBATCH * TOPK_N * 6;

    const size_t total_rows = (size_t)NBATCH * NPRED;         // 268800
    const size_t keys_bytes = total_rows * sizeof(uint64_t);  // 2,150,400
    const size_t recs_bytes = total_rows * REC_F * sizeof(float); // 8,601,600
    const size_t idx_bytes  = (size_t)NBATCH * TOPK_N * sizeof(int); // 128,000
    const size_t mask_bytes = (size_t)NBATCH * 16 * TOPK_N * sizeof(uint64_t); // 4,096,000

    if (ws_size >= keys_bytes + recs_bytes + idx_bytes + mask_bytes) {
        uint64_t* keys = (uint64_t*)d_ws;
        float* recs    = (float*)((char*)d_ws + keys_bytes);
        int* top_idx   = (int*)((char*)d_ws + keys_bytes + recs_bytes);
        uint64_t* mask = (uint64_t*)((char*)d_ws + keys_bytes + recs_bytes + idx_bytes);

        decode_kernel<<<(int)(total_rows / ROWS_PB), 256, 0, stream>>>(pred, keys, recs);
        select_kernel<<<NBATCH, 1024, 0, stream>>>(keys, top_idx);
        maskbuild_kernel<<<dim3(16, NBATCH), 256, 0, stream>>>(recs, top_idx, mask);
        reduce_kernel<<<NBATCH, 1024, 0, stream>>>(recs, top_idx, mask, dets, keep);
    } else if (ws_size >= keys_bytes + idx_bytes) {
        uint64_t* keys = (uint64_t*)d_ws;
        int* top_idx = (int*)((char*)d_ws + keys_bytes);
        decode_kernel<<<(int)(total_rows / ROWS_PB), 256, 0, stream>>>(pred, keys, nullptr);
        select_kernel<<<NBATCH, 1024, 0, stream>>>(keys, top_idx);
        nms_kernel<<<NBATCH, 1024, 0, stream>>>(pred, top_idx, dets, keep);
    } else {
        int* top_idx = (int*)d_ws;
        topk_kernel<<<NBATCH, 1024, 0, stream>>>(pred, top_idx);
        nms_kernel<<<NBATCH, 1024, 0, stream>>>(pred, top_idx, dets, keep);
    }
}

// Round 5
// 127.486 us; speedup vs baseline: 6.6684x; 1.4302x over previous
//
#include <hip/hip_runtime.h>
#include <cstdint>

#define NUM_CLASSES 80
#define NPRED 8400
#define NBATCH 32
#define TOPK_N 1000
#define SORTN 16384
#define CONF_T 0.25f
#define NMS_T 0.45f
#define STRIDE 85

#define ROWS_PB 128
#define FLOATS_PB (ROWS_PB * STRIDE)   // 10880
#define F4_PB (FLOATS_PB / 4)          // 2720
#define REC_F 8                        // floats per record (padded to 32B)
#define MPAD 1002                      // LDS mask row pad (breaks bank pattern)

__device__ __forceinline__ uint32_t f32_sortable(float f) {
    uint32_t u = __float_as_uint(f);
    return u ^ ((u >> 31) ? 0xFFFFFFFFu : 0x80000000u);
}

// 46-bit key: (sortable(masked_score) << 14) | (16383 - e).
// Descending key order == descending score, ascending index on ties (lax.top_k).

// Full-grid decode: coalesced float4 staging of 128 rows into LDS, per-row
// argmax over 80 classes + box decode. Emits sort key and (optionally)
// a 32B record (x1,y1,x2,y2,score,class) so no later stage re-reads pred.
__global__ __launch_bounds__(256) void decode_kernel(const float* __restrict__ pred,
                                                     uint64_t* __restrict__ keys,
                                                     float* __restrict__ recs) {
    __shared__ float s[FLOATS_PB];                 // 42.5 KiB
    const int blk = blockIdx.x;
    const int tid = threadIdx.x;
    const float4* g4 = (const float4*)pred + (size_t)blk * F4_PB;
    float4* s4 = (float4*)s;
    for (int i = tid; i < F4_PB; i += 256) s4[i] = g4[i];
    __syncthreads();
    if (tid < ROWS_PB) {
        const float* p = s + tid * STRIDE;         // stride 85 % 32 = 21, coprime -> conflict-free
        float cx = p[0], cy = p[1], w = p[2], h = p[3], obj = p[4];
        float best = p[5]; int bc = 0;
        #pragma unroll
        for (int c = 1; c < NUM_CLASSES; ++c) {
            float v = p[5 + c];
            if (v > best) { best = v; bc = c; }    // first-max wins, like jnp.argmax
        }
        float w2 = __fmul_rn(w, 0.5f), h2 = __fmul_rn(h, 0.5f);
        float score = __fmul_rn(obj, best);
        float masked = (score >= CONF_T) ? score : -1.0f;
        int r = blk * ROWS_PB + tid;               // global row = b*8400 + e
        int e = r % NPRED;
        keys[r] = ((uint64_t)f32_sortable(masked) << 14) | (uint32_t)(16383 - e);
        if (recs) {
            float4* rp = (float4*)(recs + (size_t)r * REC_F);
            rp[0] = make_float4(__fsub_rn(cx, w2), __fsub_rn(cy, h2),
                                __fadd_rn(cx, w2), __fadd_rn(cy, h2));
            rp[1] = make_float4(score, (float)bc, 0.0f, 0.0f);
        }
    }
}

// One block per batch: exact radix-select (4 x 12-bit MSB passes, parallel
// suffix-scan bin selection), compact the exactly-1000 winners, bitonic-sort
// 1024, write indices in lax.top_k order.
__global__ __launch_bounds__(1024) void select_kernel(const uint64_t* __restrict__ keys,
                                                      int* __restrict__ top_idx) {
    __shared__ uint64_t k_lds[NPRED];              // 67.2 KiB
    __shared__ uint64_t sortbuf[1024];             // 8 KiB
    __shared__ uint32_t hist[4096];                // 16 KiB
    __shared__ uint32_t wtot[16];
    __shared__ uint32_t sh_rem, sh_cnt;
    __shared__ uint64_t sh_prefix;
    const int b = blockIdx.x;
    const int tid = threadIdx.x;
    const int lane = tid & 63, wid = tid >> 6;

    for (int e = tid; e < NPRED; e += 1024) k_lds[e] = keys[(size_t)b * NPRED + e];
    if (tid == 0) { sh_rem = TOPK_N; sh_prefix = 0; sh_cnt = 0; }
    sortbuf[tid] = 0;                              // pads sink (real keys are much larger)
    __syncthreads();

    for (int shift = 36; shift >= 0; shift -= 12) {
        #pragma unroll
        for (int i = 0; i < 4; ++i) hist[tid * 4 + i] = 0;
        __syncthreads();                            // zero visible; prev-pass sh_* writes visible
        const uint64_t himask = (shift == 36) ? 0ull : (~0ull << (shift + 12));
        const uint64_t pref = sh_prefix;
        const uint32_t rem = sh_rem;
        for (int e = tid; e < NPRED; e += 1024) {
            uint64_t k = k_lds[e];
            if ((k & himask) == (pref & himask))
                atomicAdd(&hist[(uint32_t)(k >> shift) & 4095u], 1u);
        }
        __syncthreads();
        // each thread owns bins [4*tid .. 4*tid+3]; suffix sums descending
        uint32_t h0 = hist[tid * 4 + 0], h1 = hist[tid * 4 + 1];
        uint32_t h2 = hist[tid * 4 + 2], h3 = hist[tid * 4 + 3];
        uint32_t s4 = h0 + h1 + h2 + h3;
        uint32_t v = s4;
        #pragma unroll
        for (int off = 1; off < 64; off <<= 1) {   // wave inclusive suffix scan
            uint32_t u = __shfl_down(v, off);
            if (lane + off < 64) v += u;
        }
        if (lane == 0) wtot[wid] = v;
        __syncthreads();
        uint32_t carry = 0;
        for (int w = wid + 1; w < 16; ++w) carry += wtot[w];
        uint32_t S0 = v + carry;                   // sum of hist over bins >= 4*tid
        uint32_t carry_after = S0 - s4;            // sum over bins > 4*tid+3
        if (carry_after < rem && S0 >= rem) {      // exactly one thread: crossing in my 4 bins
            uint32_t hh[4] = {h0, h1, h2, h3};
            uint32_t pre = 0, bestS = S0, besth = h0;
            int besti = 0;
            #pragma unroll
            for (int i = 0; i < 4; ++i) {          // largest i with S(4t+i) >= rem
                uint32_t Si = S0 - pre;
                if (Si >= rem) { besti = i; bestS = Si; besth = hh[i]; }
                pre += hh[i];
            }
            sh_prefix = pref | ((uint64_t)(uint32_t)(tid * 4 + besti) << shift);
            sh_rem = rem - (bestS - besth);        // rem minus count strictly above chosen bin
        }
        __syncthreads();
    }

    const uint64_t T = sh_prefix;                  // exactly 1000 keys >= T (keys unique)
    for (int e = tid; e < NPRED; e += 1024) {
        uint64_t k = k_lds[e];
        if (k >= T) {
            uint32_t pos = atomicAdd(&sh_cnt, 1u);
            if (pos < 1024) sortbuf[pos] = k;
        }
    }
    __syncthreads();

    for (unsigned k = 2; k <= 1024; k <<= 1) {     // bitonic sort descending
        for (unsigned j = k >> 1; j > 0; j >>= 1) {
            unsigned i = tid, ixj = i ^ j;
            if (ixj > i) {
                uint64_t a = sortbuf[i], c = sortbuf[ixj];
                bool desc = ((i & k) == 0);
                if (desc ? (a < c) : (a > c)) { sortbuf[i] = c; sortbuf[ixj] = a; }
            }
            __syncthreads();
        }
    }

    if (tid < TOPK_N)
        top_idx[b * TOPK_N + tid] = 16383 - (int)((uint32_t)sortbuf[tid] & 16383u);
}

// Mask build, conflict-free: block (w=col-block, b=batch). 64 column boxes staged
// in LDS (offset coords + area precomputed once per box); each thread owns 4 rows
// in registers and sweeps columns -> all LDS reads are same-address broadcasts.
__global__ __launch_bounds__(256) void maskbuild_kernel(const float* __restrict__ recs,
                                                        const int* __restrict__ top_idx,
                                                        uint64_t* __restrict__ mask) {
    __shared__ float cx1[64], cy1[64], cx2[64], cy2[64], car[64], ccl[64];
    const int w = blockIdx.x, b = blockIdx.y;
    const int tid = threadIdx.x;
    const int jbase = w * 64;
    const int jend = min(TOPK_N - jbase, 64);

    if (tid < jend) {
        int e = top_idx[b * TOPK_N + jbase + tid];
        const float4* rp = (const float4*)(recs + ((size_t)b * NPRED + e) * REC_F);
        float4 r0 = rp[0], r1 = rp[1];
        float off = __fmul_rn(r1.y, 10.0f);        // exact: class*10 <= 790
        float x1 = __fadd_rn(r0.x, off), y1 = __fadd_rn(r0.y, off);
        float x2 = __fadd_rn(r0.z, off), y2 = __fadd_rn(r0.w, off);
        cx1[tid] = x1; cy1[tid] = y1; cx2[tid] = x2; cy2[tid] = y2;
        car[tid] = __fmul_rn(__fsub_rn(x2, x1), __fsub_rn(y2, y1));
        ccl[tid] = r1.y;
    }
    __syncthreads();

    float rx1[4], ry1[4], rx2[4], ry2[4], rar[4], rcl[4];
    bool rv[4];
    #pragma unroll
    for (int q = 0; q < 4; ++q) {
        int r = tid + q * 256;
        rv[q] = (r < TOPK_N);
        if (rv[q]) {
            int e = top_idx[b * TOPK_N + r];
            const float4* rp = (const float4*)(recs + ((size_t)b * NPRED + e) * REC_F);
            float4 r0 = rp[0], r1 = rp[1];
            float off = __fmul_rn(r1.y, 10.0f);
            float x1 = __fadd_rn(r0.x, off), y1 = __fadd_rn(r0.y, off);
            float x2 = __fadd_rn(r0.z, off), y2 = __fadd_rn(r0.w, off);
            rx1[q] = x1; ry1[q] = y1; rx2[q] = x2; ry2[q] = y2;
            rar[q] = __fmul_rn(__fsub_rn(x2, x1), __fsub_rn(y2, y1));
            rcl[q] = r1.y;
        }
    }

    uint64_t bits[4] = {0, 0, 0, 0};
    for (int bb = 0; bb < jend; ++bb) {
        float jx1 = cx1[bb], jy1 = cy1[bb], jx2 = cx2[bb], jy2 = cy2[bb];
        float jar = car[bb], jcl = ccl[bb];
        int j = jbase + bb;
        #pragma unroll
        for (int q = 0; q < 4; ++q) {
            int r = tid + q * 256;
            if (!rv[q] || j <= r || jcl != rcl[q]) continue;  // diff class => disjoint after offset
            float ix1 = fmaxf(rx1[q], jx1), iy1 = fmaxf(ry1[q], jy1);
            float ix2 = fminf(rx2[q], jx2), iy2 = fminf(ry2[q], jy2);
            float dx = fmaxf(__fsub_rn(ix2, ix1), 0.0f);
            float dy = fmaxf(__fsub_rn(iy2, iy1), 0.0f);
            float inter = __fmul_rn(dx, dy);
            float uni = __fsub_rn(__fadd_rn(rar[q], jar), inter);
            float iou = __fdiv_rn(inter, fmaxf(uni, 1e-9f));
            if (iou > NMS_T) bits[q] |= (1ull << bb);
        }
    }
    #pragma unroll
    for (int q = 0; q < 4; ++q) {
        int r = tid + q * 256;
        if (rv[q]) mask[((size_t)b * 16 + w) * TOPK_N + r] = bits[q];
    }
}

// One block per batch: gather records, ballot invalid, mask -> LDS, one-wave
// greedy reduce with register-local current word (shfl only once per 64 cols),
// write dets + keep.
__global__ __launch_bounds__(1024) void reduce_kernel(const float* __restrict__ recs,
                                                      const int* __restrict__ top_idx,
                                                      const uint64_t* __restrict__ mask,
                                                      float* __restrict__ dets,
                                                      float* __restrict__ keep_out) {
    __shared__ uint64_t lmask[16 * MPAD];          // 125.3 KiB
    __shared__ uint64_t removed_w[16];
    const int b = blockIdx.x, tid = threadIdx.x;

    float4 r0 = make_float4(0, 0, 0, 0), r1 = make_float4(0, 0, 0, 0);
    bool invalid = false;
    if (tid < TOPK_N) {
        int e = top_idx[b * TOPK_N + tid];
        const float4* rp = (const float4*)(recs + ((size_t)b * NPRED + e) * REC_F);
        r0 = rp[0]; r1 = rp[1];
        invalid = (r1.x < CONF_T);
    }
    {
        uint64_t bal = __ballot(invalid);
        if ((tid & 63) == 0) removed_w[tid >> 6] = bal;
    }
    for (int p = tid; p < 16 * TOPK_N; p += 1024) {
        int w = p / TOPK_N, i = p - w * TOPK_N;
        lmask[w * MPAD + i] = mask[((size_t)b * 16 + w) * TOPK_N + i];
    }
    __syncthreads();

    // Greedy scan, one wave. Lanes 0..15 own removed words; ALL lanes maintain a
    // register copy `cur` of the current column-block's word via the broadcast
    // LDS read lmask[W][i] (same address across lanes -> free). The dependent
    // chain is pure VALU (test bit -> select -> or); the only cross-lane op is
    // one shfl per 64 columns.
    if (tid < 64) {
        const int l = tid & 15;
        uint64_t rem = (tid < 16) ? removed_w[tid] : 0;
        for (int W = 0; W < 16; ++W) {
            uint64_t cur = __shfl(rem, W);         // word W incl. all earlier suppressions
            const int base = W * 64;
            const int nb = min(64, TOPK_N - base);
            #pragma unroll 8
            for (int bb = 0; bb < nb; ++bb) {
                int i = base + bb;
                uint64_t mW = lmask[W * MPAD + i]; // broadcast read (prefetchable)
                uint64_t ml = lmask[l * MPAD + i]; // own-row read (prefetchable)
                uint64_t sel = ((cur >> bb) & 1ull) ? 0ull : ~0ull;  // alive?
                cur |= (mW & sel);                 // mask[i] has no bits <= i, so bb-order safe
                rem |= (ml & sel);
            }
        }
        if (tid < 16) removed_w[tid] = rem;
    }
    __syncthreads();

    if (tid < TOPK_N) {
        bool kept = ((removed_w[tid >> 6] >> (tid & 63)) & 1ull) == 0;
        float* dr = dets + ((size_t)b * TOPK_N + tid) * 6;
        if (kept) {
            dr[0] = r0.x; dr[1] = r0.y; dr[2] = r0.z; dr[3] = r0.w;
            dr[4] = r1.x; dr[5] = r1.y;
        } else {
            dr[0] = 0.0f; dr[1] = 0.0f; dr[2] = 0.0f;
            dr[3] = 0.0f; dr[4] = 0.0f; dr[5] = 0.0f;
        }
        keep_out[b * TOPK_N + tid] = kept ? 1.0f : 0.0f;
    }
}

// ---------- fallback kernels (small ws) ----------

__global__ __launch_bounds__(1024) void topk_kernel(const float* __restrict__ pred,
                                                    int* __restrict__ top_idx) {
    __shared__ uint64_t keys[SORTN];
    const int b = blockIdx.x;
    const int tid = threadIdx.x;
    const float* pb = pred + (size_t)b * NPRED * STRIDE;

    for (int e = tid; e < SORTN; e += 1024) {
        uint64_t key = 0;
        if (e < NPRED) {
            const float* p = pb + (size_t)e * STRIDE;
            float obj = p[4];
            float best = p[5];
            #pragma unroll 8
            for (int c = 1; c < NUM_CLASSES; ++c) best = fmaxf(best, p[5 + c]);
            float score = __fmul_rn(obj, best);
            float masked = (score >= CONF_T) ? score : -1.0f;
            key = ((uint64_t)f32_sortable(masked) << 32) | (uint32_t)(~(uint32_t)e);
        }
        keys[e] = key;
    }
    __syncthreads();
    for (unsigned k = 2; k <= SORTN; k <<= 1) {
        for (unsigned j = k >> 1; j > 0; j >>= 1) {
            for (unsigned i = tid; i < SORTN; i += 1024) {
                unsigned ixj = i ^ j;
                if (ixj > i) {
                    uint64_t a = keys[i], c = keys[ixj];
                    bool desc = ((i & k) == 0);
                    if (desc ? (a < c) : (a > c)) { keys[i] = c; keys[ixj] = a; }
                }
            }
            __syncthreads();
        }
    }
    for (int t = tid; t < TOPK_N; t += 1024) {
        top_idx[b * TOPK_N + t] = (int)(~(uint32_t)keys[t]);
    }
}

__global__ __launch_bounds__(1024) void nms_kernel(const float* __restrict__ pred,
                                                   const int* __restrict__ top_idx,
                                                   float* __restrict__ dets,
                                                   float* __restrict__ keep_out) {
    __shared__ uint64_t mask[TOPK_N * 16];
    __shared__ float lx1[TOPK_N], ly1[TOPK_N], lx2[TOPK_N], ly2[TOPK_N];
    __shared__ float lsc[TOPK_N], lcl[TOPK_N];
    __shared__ uint64_t removed_w[16];

    const int b = blockIdx.x;
    const int tid = threadIdx.x;
    const float* pb = pred + (size_t)b * NPRED * STRIDE;

    bool invalid = false;
    if (tid < TOPK_N) {
        int e = top_idx[b * TOPK_N + tid];
        const float* p = pb + (size_t)e * STRIDE;
        float cx = p[0], cy = p[1], w = p[2], h = p[3], obj = p[4];
        float best = p[5]; int bc = 0;
        for (int c = 1; c < NUM_CLASSES; ++c) {
            float v = p[5 + c];
            if (v > best) { best = v; bc = c; }
        }
        float w2 = __fmul_rn(w, 0.5f), h2 = __fmul_rn(h, 0.5f);
        float score = __fmul_rn(obj, best);
        lx1[tid] = __fsub_rn(cx, w2);
        ly1[tid] = __fsub_rn(cy, h2);
        lx2[tid] = __fadd_rn(cx, w2);
        ly2[tid] = __fadd_rn(cy, h2);
        lsc[tid] = score;
        lcl[tid] = (float)bc;
        invalid = (score < CONF_T);
    }
    {
        uint64_t bal = __ballot(invalid);
        if ((tid & 63) == 0) removed_w[tid >> 6] = bal;
    }
    __syncthreads();

    for (int p = tid; p < TOPK_N * 16; p += 1024) {
        int i = p >> 4, w = p & 15;
        float ci = lcl[i];
        float offi = __fmul_rn(ci, 10.0f);
        float ax1 = __fadd_rn(lx1[i], offi), ay1 = __fadd_rn(ly1[i], offi);
        float ax2 = __fadd_rn(lx2[i], offi), ay2 = __fadd_rn(ly2[i], offi);
        float areai = __fmul_rn(__fsub_rn(ax2, ax1), __fsub_rn(ay2, ay1));
        uint64_t bits = 0;
        int jend = min(TOPK_N - w * 64, 64);
        for (int bb = 0; bb < jend; ++bb) {
            int j = w * 64 + bb;
            if (j <= i) continue;
            if (lcl[j] != ci) continue;
            float bx1 = __fadd_rn(lx1[j], offi), by1 = __fadd_rn(ly1[j], offi);
            float bx2 = __fadd_rn(lx2[j], offi), by2 = __fadd_rn(ly2[j], offi);
            float areaj = __fmul_rn(__fsub_rn(bx2, bx1), __fsub_rn(by2, by1));
            float ix1 = fmaxf(ax1, bx1), iy1 = fmaxf(ay1, by1);
            float ix2 = fminf(ax2, bx2), iy2 = fminf(ay2, by2);
            float dx = fmaxf(__fsub_rn(ix2, ix1), 0.0f);
            float dy = fmaxf(__fsub_rn(iy2, iy1), 0.0f);
            float inter = __fmul_rn(dx, dy);
            float uni = __fsub_rn(__fadd_rn(areai, areaj), inter);
            float iou = __fdiv_rn(inter, fmaxf(uni, 1e-9f));
            if (iou > NMS_T) bits |= (1ull << bb);
        }
        mask[i * 16 + w] = bits;
    }
    __syncthreads();

    if (tid < 64) {
        int lane = tid;
        uint64_t rem = (lane < 16) ? removed_w[lane] : 0;
        for (int i = 0; i < TOPK_N; ++i) {
            uint64_t rw = __shfl(rem, i >> 6);
            bool alive = ((rw >> (i & 63)) & 1ull) == 0;
            uint64_t m = mask[i * 16 + (lane & 15)];
            if (alive && lane < 16) rem |= m;
        }
        if (lane < 16) removed_w[lane] = rem;
    }
    __syncthreads();

    for (int t = tid; t < TOPK_N; t += 1024) {
        bool kept = ((removed_w[t >> 6] >> (t & 63)) & 1ull) == 0;
        float* dr = dets + ((size_t)b * TOPK_N + t) * 6;
        if (kept) {
            dr[0] = lx1[t]; dr[1] = ly1[t]; dr[2] = lx2[t]; dr[3] = ly2[t];
            dr[4] = lsc[t]; dr[5] = lcl[t];
        } else {
            dr[0] = 0.0f; dr[1] = 0.0f; dr[2] = 0.0f;
            dr[3] = 0.0f; dr[4] = 0.0f; dr[5] = 0.0f;
        }
        keep_out[b * TOPK_N + t] = kept ? 1.0f : 0.0f;
    }
}

extern "C" void kernel_launch(void* const* d_in, const int* in_sizes, int n_in,
                              void* d_out, int out_size, void* d_ws, size_t ws_size,
                              hipStream_t stream) {
    const float* pred = (const float*)d_in[0];
    float* dets = (float*)d_out;                              // 32*1000*6
    float* keep = (float*)d_out + (size_t)NBATCH * TOPK_N * 6;

    const size_t total_rows = (size_t)NBATCH * NPRED;         // 268800
    const size_t keys_bytes = total_rows * sizeof(uint64_t);  // 2,150,400
    const size_t recs_bytes = total_rows * REC_F * sizeof(float); // 8,601,600
    const size_t idx_bytes  = (size_t)NBATCH * TOPK_N * sizeof(int); // 128,000
    const size_t mask_bytes = (size_t)NBATCH * 16 * TOPK_N * sizeof(uint64_t); // 4,096,000

    if (ws_size >= keys_bytes + recs_bytes + idx_bytes + mask_bytes) {
        uint64_t* keys = (uint64_t*)d_ws;
        float* recs    = (float*)((char*)d_ws + keys_bytes);
        int* top_idx   = (int*)((char*)d_ws + keys_bytes + recs_bytes);
        uint64_t* mask = (uint64_t*)((char*)d_ws + keys_bytes + recs_bytes + idx_bytes);

        decode_kernel<<<(int)(total_rows / ROWS_PB), 256, 0, stream>>>(pred, keys, recs);
        select_kernel<<<NBATCH, 1024, 0, stream>>>(keys, top_idx);
        maskbuild_kernel<<<dim3(16, NBATCH), 256, 0, stream>>>(recs, top_idx, mask);
        reduce_kernel<<<NBATCH, 1024, 0, stream>>>(recs, top_idx, mask, dets, keep);
    } else if (ws_size >= keys_bytes + idx_bytes) {
        uint64_t* keys = (uint64_t*)d_ws;
        int* top_idx = (int*)((char*)d_ws + keys_bytes);
        decode_kernel<<<(int)(total_rows / ROWS_PB), 256, 0, stream>>>(pred, keys, nullptr);
        select_kernel<<<NBATCH, 1024, 0, stream>>>(keys, top_idx);
        nms_kernel<<<NBATCH, 1024, 0, stream>>>(pred, top_idx, dets, keep);
    } else {
        int* top_idx = (int*)d_ws;
        topk_kernel<<<NBATCH, 1024, 0, stream>>>(pred, top_idx);
        nms_kernel<<<NBATCH, 1024, 0, stream>>>(pred, top_idx, dets, keep);
    }
}